// Round 9
// baseline (293.607 us; speedup 1.0000x reference)
//
#include <hip/hip_runtime.h>
#include <hip/hip_bf16.h>

#define BB 8
#define SS 2048
#define NN 1024
#define MT (BB*SS)   // 16384
#define NPC 32       // partial chunks per row (16 kc-tiles * 2 wave-columns)
#define NT2 32       // K tiles of 32

typedef __attribute__((ext_vector_type(8))) short bf16x8;
typedef __attribute__((ext_vector_type(4))) float f32x4;
typedef unsigned short u16;
typedef unsigned int u32;

__device__ __forceinline__ u16 f2bf(float f) {
  u32 u = __float_as_uint(f);
  u += 0x7fff + ((u >> 16) & 1);
  return (u16)(u >> 16);
}
__device__ __forceinline__ float bf2f(u16 h) {
  return __uint_as_float(((u32)h) << 16);
}

typedef __attribute__((address_space(1))) void GV;
typedef __attribute__((address_space(3))) void LV;
__device__ __forceinline__ void cp16(const void* g, void* l) {
  __builtin_amdgcn_global_load_lds((GV*)g, (LV*)l, 16, 0, 0);
}

#define WAIT4 asm volatile("s_waitcnt vmcnt(4)" ::: "memory")
#define WAIT0 asm volatile("s_waitcnt vmcnt(0)" ::: "memory")
#define LGKM0 asm volatile("s_waitcnt lgkmcnt(0)" ::: "memory")
#define BARX  __builtin_amdgcn_s_barrier()
#define SCB0  __builtin_amdgcn_sched_barrier(0)

// ------- fused prep: blocks <4096 cast outer (+rowsum, kb=mask); rest cast W --
__global__ __launch_bounds__(256) void prep_kernel(const float* __restrict__ outer,
                                                   const float* __restrict__ mask,
                                                   const float* __restrict__ Wq,
                                                   const float* __restrict__ Wk,
                                                   const float* __restrict__ bq,
                                                   const float* __restrict__ bk,
                                                   u16* __restrict__ Xb,
                                                   float* __restrict__ r,
                                                   float* __restrict__ kb,
                                                   u16* __restrict__ Wb,
                                                   float* __restrict__ bb) {
  int bid = blockIdx.x;
  if (bid < 4096) {
    int w = threadIdx.x >> 6, lane = threadIdx.x & 63;
    int row = bid * 4 + w;
    const float4* src = (const float4*)(outer + (size_t)row * NN);
    ushort4* dst = (ushort4*)(Xb + (size_t)row * NN);
    float s = 0.f;
#pragma unroll
    for (int u = 0; u < 4; u++) {
      int idx = lane + u * 64;
      float4 v = src[idx];
      ushort4 o;
      o.x = f2bf(v.x); o.y = f2bf(v.y); o.z = f2bf(v.z); o.w = f2bf(v.w);
      dst[idx] = o;
      s += (v.x + v.y) + (v.z + v.w);
    }
#pragma unroll
    for (int off = 1; off < 64; off <<= 1) s += __shfl_xor(s, off);
    if (lane == 0) { r[row] = s; kb[row] = mask[row]; }
  } else {
    int idx = (bid - 4096) * 256 + threadIdx.x;   // 0 .. 524287 (x4 elems)
    int e = idx * 4;
    int rowm = e >> 10;
    int col = e & 1023;
    const float* srcp = (rowm < NN) ? (Wq + (size_t)rowm * NN + col)
                                    : (Wk + (size_t)(rowm - NN) * NN + col);
    float4 v = *(const float4*)srcp;
    ushort4 o; o.x = f2bf(v.x); o.y = f2bf(v.y); o.z = f2bf(v.z); o.w = f2bf(v.w);
    *(ushort4*)(Wb + (size_t)e) = o;
    if (idx < 2 * NN) bb[idx] = (idx < NN) ? bq[idx] : bk[idx - NN];
  }
}

// ======== 128x128 / BK=32 / 4 waves / 32KB LDS / high-occupancy core =========
// Rationale: the 256^2 structure is register-bound to 8 waves/CU (1 block) ->
// every wait is uncovered (all schedules measured 87-94us, no pipe >35%).
// This m97-class config (acc 64 regs, ~<=130 total, 32KB LDS) co-schedules
// 3-4 blocks/CU = 12-16 waves -> cross-block overlap hides latency (m114).
// Per K-tile/wave: 8 ds_read_b128, 16 MFMA, 4 cp16, 2 barriers, 1 counted wait.
// LDS [buf][A 8KB | B 8KB], 64B rows. Read swizzle: 16B-slot ^= (row>>1)&3 ->
// 2 lanes/bank pos = free (m136). Stage keeps linear dest (tid*16B), source
// pre-applies the same involution (rule 21): src slot = (tid&3)^((r>>1)&3).
// Ring: STAGE(t+2 -> buf[t&1]) issued AFTER the post-MFMA barrier (all waves'
// reads of buf drained via their lgkm0 before that barrier); WAIT4 retires
// STAGE(t+1), leaves STAGE(t+2) in flight across the tile boundary.
template<int LDG>
__device__ __forceinline__ void gemm_core(const u16* gA, const u16* gB,
                                          u16* lds, int tid,
                                          f32x4 (&acc)[4][4]) {
  const int lane = tid & 63, w = tid >> 6;
  const int wr = w >> 1, wc = w & 1;
  const int l15 = lane & 15, quad = lane >> 4;
  const int so = (quad ^ ((l15 >> 1) & 3)) * 8;   // swizzled 16B read slot
  const int rr = tid >> 2, sl = tid & 3;
  const int sx = sl ^ ((rr >> 1) & 3);            // inverse-swizzled src slot
  const u16* gAs = gA + (size_t)rr * LDG + sx * 8;
  const u16* gBs = gB + (size_t)rr * LDG + sx * 8;
  u16* dA = lds + tid * 8;                        // +buf*8192 (+2048 second row)
  u16* dB = lds + 4096 + tid * 8;
  const u16* pA = lds + (wr * 64 + l15) * 32 + so;        // +buf*8192 + i*512
  const u16* pB = lds + 4096 + (wc * 64 + l15) * 32 + so; // +buf*8192 + j*512

  auto STAGE = [&](int buf, int kt) {
    cp16(gAs + kt * 32,                      dA + buf * 8192);
    cp16(gAs + (size_t)64 * LDG + kt * 32,   dA + buf * 8192 + 2048);
    cp16(gBs + kt * 32,                      dB + buf * 8192);
    cp16(gBs + (size_t)64 * LDG + kt * 32,   dB + buf * 8192 + 2048);
  };

  STAGE(0, 0); STAGE(1, 1);
  WAIT4;                                   // tile0 landed; tile1's 4 in flight
#pragma unroll 1
  for (int t = 0; t < NT2; ++t) {
    const int buf = t & 1;
    BARX;
    bf16x8 af[4], bf[4];
#pragma unroll
    for (int i = 0; i < 4; ++i) af[i] = *(const bf16x8*)(pA + buf * 8192 + i * 512);
#pragma unroll
    for (int j = 0; j < 4; ++j) bf[j] = *(const bf16x8*)(pB + buf * 8192 + j * 512);
    LGKM0; SCB0;
    __builtin_amdgcn_s_setprio(1);
#pragma unroll
    for (int i = 0; i < 4; ++i)
#pragma unroll
      for (int j = 0; j < 4; ++j)
        acc[i][j] = __builtin_amdgcn_mfma_f32_16x16x32_bf16(af[i], bf[j], acc[i][j], 0, 0, 0);
    __builtin_amdgcn_s_setprio(0);
    BARX;
    if (t < NT2 - 2)       { STAGE(buf, t + 2); WAIT4; }
    else if (t == NT2 - 2) { WAIT0; }
  }
}

// ---------------- stage 1 GEMM: C[row][m] = sigmoid(X.Wb^T + bb) - 0.5 (bf16) --
__global__ __launch_bounds__(256, 3) void gemm1_kernel(const u16* __restrict__ X,
                                                       const u16* __restrict__ W,
                                                       const float* __restrict__ bb,
                                                       u16* __restrict__ C,
                                                       float* __restrict__ kb) {
  __shared__ u16 lds[2 * 8192];
  int bid = blockIdx.x;                 // 2048
  int xcd = bid & 7, idx = bid >> 3;    // XCD-affine: per-XCD 16 tm x 16 tn
  int tm = xcd * 16 + (idx & 15);       // 0..127
  int tn = idx >> 4;                    // 0..15
  int tid = threadIdx.x;
  f32x4 acc[4][4] = {};
  gemm_core<1024>(X + (size_t)tm * 128 * 1024, W + (size_t)tn * 128 * 1024,
                  lds, tid, acc);

  int lane = tid & 63, w = tid >> 6;
  int wr = w >> 1, wc = w & 1, l15 = lane & 15, quad = lane >> 4;
  int colb = tn * 128 + wc * 64 + l15;
  bool khalf = (tn >= 8);               // k' half when tn>=8
  int rowb = tm * 128 + wr * 64 + quad * 4;
#pragma unroll
  for (int i = 0; i < 4; ++i) {
    float rsum[4] = {0.f, 0.f, 0.f, 0.f};
#pragma unroll
    for (int j = 0; j < 4; ++j) {
      int col = colb + j * 16;
      float bias = bb[col];
#pragma unroll
      for (int rg = 0; rg < 4; ++rg) {
        int row = rowb + i * 16 + rg;
        float v = acc[i][j][rg] + bias;
        float sg = 1.0f / (1.0f + __expf(-v));
        u16 h = f2bf(sg - 0.5f);
        C[(size_t)row * 2048 + col] = h;
        rsum[rg] += bf2f(h);   // rounded value, matches what flash's MFMA sees
      }
    }
    if (khalf) {
#pragma unroll
      for (int rg = 0; rg < 4; ++rg) {
        float s = rsum[rg];
#pragma unroll
        for (int off = 1; off < 16; off <<= 1) s += __shfl_xor(s, off);
        if (l15 == 0) atomicAdd(&kb[rowb + i * 16 + rg], 0.5f * s);
      }
    }
  }
}

// ---------------- flash: one 128q x 128k tile per block; XCD = batch ----
__global__ __launch_bounds__(256, 3) void flash_kernel(const u16* __restrict__ Cq,
                                                       const float* __restrict__ kb,
                                                       const float* __restrict__ r,
                                                       float* __restrict__ pm,
                                                       float* __restrict__ pl,
                                                       float* __restrict__ pt) {
  __shared__ u16 lds[2 * 8192];
  int bid = blockIdx.x;            // 2048
  int b = bid & 7;                 // XCD-affine: each XCD owns one batch
  int idx = bid >> 3;
  int qt = idx >> 4;               // 0..15
  int kc = idx & 15;               // inner: q-tile reused from L2
  int tid = threadIdx.x;
  f32x4 acc[4][4] = {};
  gemm_core<2048>(Cq + (size_t)(b * SS + qt * 128) * 2048,
                  Cq + (size_t)(b * SS + kc * 128) * 2048 + 1024,
                  lds, tid, acc);

  int lane = tid & 63, w = tid >> 6;
  int wr = w >> 1, wc = w & 1, l15 = lane & 15, quad = lane >> 4;
  float kbv[4], rv[4];
  int colg = b * SS + kc * 128 + wc * 64 + l15;
#pragma unroll
  for (int j = 0; j < 4; ++j) { kbv[j] = kb[colg + j * 16]; rv[j] = r[colg + j * 16]; }
  int chunk = kc * 2 + wc;
  int rowb = b * SS + qt * 128 + wr * 64 + quad * 4;
#pragma unroll
  for (int i = 0; i < 4; ++i) {
#pragma unroll
    for (int rg = 0; rg < 4; ++rg) {
      float lg[4];
      float tmax = -1e30f;
#pragma unroll
      for (int j = 0; j < 4; ++j) { lg[j] = acc[i][j][rg] + kbv[j]; tmax = fmaxf(tmax, lg[j]); }
#pragma unroll
      for (int off = 1; off < 16; off <<= 1) tmax = fmaxf(tmax, __shfl_xor(tmax, off));
      float rs = 0.f, rt = 0.f;
#pragma unroll
      for (int j = 0; j < 4; ++j) {
        float p = __expf(lg[j] - tmax);
        rs += p; rt += p * rv[j];
      }
#pragma unroll
      for (int off = 1; off < 16; off <<= 1) { rs += __shfl_xor(rs, off); rt += __shfl_xor(rt, off); }
      if (l15 == 0) {
        int grow = rowb + i * 16 + rg;
        pm[(size_t)grow * NPC + chunk] = tmax;
        pl[(size_t)grow * NPC + chunk] = rs;
        pt[(size_t)grow * NPC + chunk] = rt;
      }
    }
  }
}

// ---------------- combine key-chunk partials ----------------
__global__ __launch_bounds__(256) void fixup_kernel(const float* __restrict__ pm,
                                                    const float* __restrict__ pl,
                                                    const float* __restrict__ pt,
                                                    float* __restrict__ out) {
  int row = blockIdx.x * 256 + threadIdx.x;
  float Mx = -1e30f;
#pragma unroll
  for (int c = 0; c < NPC; c++) Mx = fmaxf(Mx, pm[row * NPC + c]);
  float L = 0.f, T = 0.f;
#pragma unroll
  for (int c = 0; c < NPC; c++) {
    float a = __expf(pm[row * NPC + c] - Mx);
    L += pl[row * NPC + c] * a;
    T += pt[row * NPC + c] * a;
  }
  out[row] = T / L;
}

extern "C" void kernel_launch(void* const* d_in, const int* in_sizes, int n_in,
                              void* d_out, int out_size, void* d_ws, size_t ws_size,
                              hipStream_t stream) {
  const float* outer = (const float*)d_in[0];
  const float* mask  = (const float*)d_in[1];
  const float* Wk    = (const float*)d_in[2];
  const float* bk    = (const float*)d_in[3];
  const float* Wq    = (const float*)d_in[4];
  const float* bq    = (const float*)d_in[5];
  float* out = (float*)d_out;

  char* ws = (char*)d_ws;
  size_t off = 0;
  auto alloc = [&](size_t bytes) -> void* {
    void* p = ws + off;
    off = (off + bytes + 255) & ~(size_t)255;
    return p;
  };
  u16* Xb  = (u16*)alloc((size_t)MT * NN * 2);       // 32 MB bf16 outer
  u16* Wb  = (u16*)alloc((size_t)2048 * NN * 2);     // 4 MB bf16 [Wq;Wk]
  u16* Cq  = (u16*)alloc((size_t)MT * 2048 * 2);     // 64 MB bf16 [q'|k']
  float* bb = (float*)alloc(2048 * 4);
  float* rr = (float*)alloc((size_t)MT * 4);
  float* kb = (float*)alloc((size_t)MT * 4);
  float* pm = (float*)alloc((size_t)MT * NPC * 4);
  float* pl = (float*)alloc((size_t)MT * NPC * 4);
  float* pt = (float*)alloc((size_t)MT * NPC * 4);

  prep_kernel<<<dim3(6144), dim3(256), 0, stream>>>(outer, mask, Wq, Wk, bq, bk,
                                                    Xb, rr, kb, Wb, bb);
  gemm1_kernel<<<dim3(2048), dim3(256), 0, stream>>>(Xb, Wb, bb, Cq, kb);
  flash_kernel<<<dim3(2048), dim3(256), 0, stream>>>(Cq, kb, rr, pm, pl, pt);
  fixup_kernel<<<dim3(MT / 256), dim3(256), 0, stream>>>(pm, pl, pt, out);
}